// Round 9
// baseline (471.241 us; speedup 1.0000x reference)
//
#include <hip/hip_runtime.h>
#include <hip/hip_fp16.h>

#define K_NB 81
#define OUTC 8
#define BLK 256
#define KT 16   // k-tile staged in LDS; 80 = 5*16 (k=0 handled in prologue)

typedef float v2f __attribute__((ext_vector_type(2)));
typedef float v4f __attribute__((ext_vector_type(4)));

// W2[k][c][l] = dw[k][c] * weight[c][k][l], flat as w2[k*32 + c*8 + l]
__global__ void prep_w2(const float* __restrict__ dw,
                        const float* __restrict__ wt,
                        float* __restrict__ w2) {
    int i = blockIdx.x * blockDim.x + threadIdx.x;
    if (i < K_NB * 32) {
        int k = i >> 5;
        int c = (i >> 3) & 3;
        int l = i & 7;
        w2[i] = dw[k * 4 + c] * wt[(c * K_NB + k) * OUTC + l];
    }
}

union F2H { float f; __half2 h; };

// points [N,3] fp32 -> ph[N] = {half x, half y, half z, half 0} (8B, aligned)
__global__ void repack_points(const float* __restrict__ pts,
                              v2f* __restrict__ ph, int N) {
    int n = blockIdx.x * blockDim.x + threadIdx.x;
    if (n >= N) return;
    float x = __builtin_nontemporal_load(&pts[3 * n + 0]);
    float y = __builtin_nontemporal_load(&pts[3 * n + 1]);
    float z = __builtin_nontemporal_load(&pts[3 * n + 2]);
    F2H a, b;
    a.h = __floats2half2_rn(x, y);
    b.h = __floats2half2_rn(z, 0.f);
    v2f v; v.x = a.f; v.y = b.f;
    ph[n] = v;   // PLAIN store: ph should land in L2 (gathered next)
}

// MSHR-WALL MODEL (R1-R5): gather rate = 0.264 req/cy/CU x ~250cy blended
// latency ~= 64 outstanding = per-CU pending-request cap. Schedule proved
// irrelevant (R1/R2/R3 all 249us). Only lever: LATENCY = ph's L2 hit rate.
// R5: `nt` alone still ALLOCATES in L2 -> index stream flushes ph (FETCH
// stuck 321MB, ~5.5% gather HBM-miss). R7/R8: asm `nt sc1` loads -> GPU
// fault/abort twice (likely reserved cache-policy encoding). THIS ROUND:
// compiler-generated system-scope load (__hip_atomic_load relaxed/system)
// on index staging only — legal encoding, vmcnt-tracked, same intent:
// keep the 162MB stream from allocating in L2. Everything else = R5-passed.
__global__ __launch_bounds__(BLK) void conv_main_h(
    const float* __restrict__ points,
    const v2f*   __restrict__ ph,
    const int*   __restrict__ indices,
    const float* __restrict__ w2,
    const float* __restrict__ bias,
    float*       __restrict__ out,
    int N) {
    __shared__ int sidx[BLK * (KT + 1)];  // pitch 17: 2-way bank alias = free

    const int tid = threadIdx.x;
    const int n0  = blockIdx.x * BLK;
    const int n   = n0 + tid;
    const bool valid = n < N;
    const int nc = valid ? n : (N - 1);

    const float px = __builtin_nontemporal_load(&points[nc * 3 + 0]);
    const float py = __builtin_nontemporal_load(&points[nc * 3 + 1]);
    const float pz = __builtin_nontemporal_load(&points[nc * 3 + 2]);

    float acc[OUTC];
#pragma unroll
    for (int l = 0; l < OUTC; ++l) {
        float a = bias[l] + w2[24 + l];           // k=0: dist feature = 1.0
        a = fmaf(px, w2[0 + l], a);
        a = fmaf(py, w2[8 + l], a);
        a = fmaf(pz, w2[16 + l], a);
        acc[l] = a;
    }

    for (int t = 0; t < 5; ++t) {
        __syncthreads();
        // Index staging: SYSTEM-scope relaxed loads -> sc-flagged encoding
        // that does not allocate the stream in L2 (protects ph residency).
#pragma unroll
        for (int i = 0; i < KT; ++i) {
            int e   = i * BLK + tid;
            int row = e >> 4;
            int col = e & 15;
            int gr  = n0 + row;
            if (gr >= N) gr = N - 1;
            sidx[row * (KT + 1) + col] =
                __hip_atomic_load(&indices[gr * K_NB + 1 + t * KT + col],
                                  __ATOMIC_RELAXED, __HIP_MEMORY_SCOPE_SYSTEM);
        }
        __syncthreads();

        // phase 1: pull all ids for this thread from LDS
        int ids[KT];
#pragma unroll
        for (int j = 0; j < KT; ++j)
            ids[j] = sidx[tid * (KT + 1) + j];

        // phase 2: issue ALL gathers back-to-back, PLAIN cached (L2-allocate)
        v2f r[KT];
#pragma unroll
        for (int j = 0; j < KT; ++j)
            r[j] = ph[ids[j]];

        // phase 3: consume (oldest first, vmcnt waits overlap issue)
#pragma unroll
        for (int j = 0; j < KT; ++j) {
            const int k = 1 + t * KT + j;
            F2H u0, u1; u0.f = r[j].x; u1.f = r[j].y;
            const float2 fxy = __half22float2(u0.h);
            const float  qx = fxy.x, qy = fxy.y;
            const float  qz = __half2float(__low2half(u1.h));
            const float dx = qx - px, dy = qy - py, dz = qz - pz;
            const float dist = fmaf(dx, dx, fmaf(dy, dy, fmaf(dz, dz, 1.0f)));
            const float* __restrict__ w = w2 + k * 32;  // uniform -> s_load
#pragma unroll
            for (int l = 0; l < OUTC; ++l) {
                acc[l] = fmaf(qx, w[l],
                         fmaf(qy, w[8 + l],
                         fmaf(qz, w[16 + l],
                         fmaf(dist, w[24 + l], acc[l]))));
            }
        }
    }

    if (valid) {
        v4f* o = (v4f*)(out + (long)n * OUTC);
        v4f lo, hi;
        lo.x = acc[0]; lo.y = acc[1]; lo.z = acc[2]; lo.w = acc[3];
        hi.x = acc[4]; hi.y = acc[5]; hi.z = acc[6]; hi.w = acc[7];
        __builtin_nontemporal_store(lo, o);
        __builtin_nontemporal_store(hi, o + 1);
    }
}

// ---------- fp32 fallback if ws too small ----------
__global__ __launch_bounds__(BLK) void conv_main_f32(
    const float* __restrict__ points,
    const int*   __restrict__ indices,
    const float* __restrict__ w2,
    const float* __restrict__ bias,
    float*       __restrict__ out,
    int N) {
    __shared__ int sidx[BLK * (KT + 1)];
    const int tid = threadIdx.x;
    const int n0  = blockIdx.x * BLK;
    const int n   = n0 + tid;
    const bool valid = n < N;
    const int nc = valid ? n : (N - 1);

    const float px = points[nc * 3 + 0];
    const float py = points[nc * 3 + 1];
    const float pz = points[nc * 3 + 2];
    float acc[OUTC];
#pragma unroll
    for (int l = 0; l < OUTC; ++l) {
        float a = bias[l] + w2[24 + l];
        a = fmaf(px, w2[0 + l], a);
        a = fmaf(py, w2[8 + l], a);
        a = fmaf(pz, w2[16 + l], a);
        acc[l] = a;
    }
    for (int t = 0; t < 5; ++t) {
        __syncthreads();
#pragma unroll
        for (int i = 0; i < KT; ++i) {
            int e = i * BLK + tid;
            int row = e >> 4, col = e & 15;
            int gr = n0 + row;
            if (gr >= N) gr = N - 1;
            sidx[row * (KT + 1) + col] = indices[gr * K_NB + 1 + t * KT + col];
        }
        __syncthreads();
#pragma unroll
        for (int j = 0; j < KT; ++j) {
            const int k  = 1 + t * KT + j;
            const int id = sidx[tid * (KT + 1) + j];
            const float qx = points[id * 3 + 0];
            const float qy = points[id * 3 + 1];
            const float qz = points[id * 3 + 2];
            const float dx = qx - px, dy = qy - py, dz = qz - pz;
            const float dist = fmaf(dx, dx, fmaf(dy, dy, fmaf(dz, dz, 1.0f)));
            const float* __restrict__ w = w2 + k * 32;
#pragma unroll
            for (int l = 0; l < OUTC; ++l) {
                acc[l] = fmaf(qx, w[l],
                         fmaf(qy, w[8 + l],
                         fmaf(qz, w[16 + l],
                         fmaf(dist, w[24 + l], acc[l]))));
            }
        }
    }
    if (valid) {
        float4* o = (float4*)(out + (long)n * OUTC);
        o[0] = make_float4(acc[0], acc[1], acc[2], acc[3]);
        o[1] = make_float4(acc[4], acc[5], acc[6], acc[7]);
    }
}

extern "C" void kernel_launch(void* const* d_in, const int* in_sizes, int n_in,
                              void* d_out, int out_size, void* d_ws, size_t ws_size,
                              hipStream_t stream) {
    const float* points  = (const float*)d_in[0];
    const int*   indices = (const int*)  d_in[1];
    const float* dw      = (const float*)d_in[2];
    const float* wt      = (const float*)d_in[3];
    const float* bias    = (const float*)d_in[4];
    float*       out     = (float*)d_out;

    const int N = in_sizes[0] / 3;

    const size_t ph_bytes = (size_t)N * 8;
    const size_t need     = ph_bytes + K_NB * 32 * sizeof(float);

    if (ws_size >= need) {
        v2f*   ph = (v2f*)d_ws;
        float* w2 = (float*)((char*)d_ws + ph_bytes);
        hipLaunchKernelGGL(prep_w2, dim3((K_NB * 32 + BLK - 1) / BLK), dim3(BLK),
                           0, stream, dw, wt, w2);
        hipLaunchKernelGGL(repack_points, dim3((N + BLK - 1) / BLK), dim3(BLK),
                           0, stream, points, ph, N);
        hipLaunchKernelGGL(conv_main_h, dim3((N + BLK - 1) / BLK), dim3(BLK),
                           0, stream, points, ph, indices, w2, bias, out, N);
    } else {
        float* w2 = (float*)d_ws;
        hipLaunchKernelGGL(prep_w2, dim3((K_NB * 32 + BLK - 1) / BLK), dim3(BLK),
                           0, stream, dw, wt, w2);
        hipLaunchKernelGGL(conv_main_f32, dim3((N + BLK - 1) / BLK), dim3(BLK),
                           0, stream, points, indices, w2, bias, out, N);
    }
}

// Round 10
// 438.096 us; speedup vs baseline: 1.0757x; 1.0757x over previous
//
#include <hip/hip_runtime.h>
#include <hip/hip_fp16.h>

#define K_NB 81
#define OUTC 8
#define BLK 256
#define KT 16   // k-tile staged in LDS; 80 = 5*16 (k=0 handled in prologue)

typedef float v2f __attribute__((ext_vector_type(2)));
typedef float v4f __attribute__((ext_vector_type(4)));

// W2[k][c][l] = dw[k][c] * weight[c][k][l], flat as w2[k*32 + c*8 + l]
__global__ void prep_w2(const float* __restrict__ dw,
                        const float* __restrict__ wt,
                        float* __restrict__ w2) {
    int i = blockIdx.x * blockDim.x + threadIdx.x;
    if (i < K_NB * 32) {
        int k = i >> 5;
        int c = (i >> 3) & 3;
        int l = i & 7;
        w2[i] = dw[k * 4 + c] * wt[(c * K_NB + k) * OUTC + l];
    }
}

union F2H { float f; __half2 h; };

// points [N,3] fp32 -> ph[N] = {half x, half y, half z, half 0} (8B, aligned)
__global__ void repack_points(const float* __restrict__ pts,
                              v2f* __restrict__ ph, int N) {
    int n = blockIdx.x * blockDim.x + threadIdx.x;
    if (n >= N) return;
    float x = __builtin_nontemporal_load(&pts[3 * n + 0]);
    float y = __builtin_nontemporal_load(&pts[3 * n + 1]);
    float z = __builtin_nontemporal_load(&pts[3 * n + 2]);
    F2H a, b;
    a.h = __floats2half2_rn(x, y);
    b.h = __floats2half2_rn(z, 0.f);
    v2f v; v.x = a.f; v.y = b.f;
    ph[n] = v;   // PLAIN store: ph should land in L2 (gathered next)
}

// FINAL MODEL (validated R1-R9): dur = requests x blended_latency / MSHR.
//   requests = 40.5M random 8B gathers (algorithmic, irreducible)
//   MSHR ~= 64/CU (hardware)
//   blended latency = f(ph L2 hit rate): 250cy @ 94.5% hit -> 247us conv.
// Quantitative confirmation: R9's system-scope idx loads dropped hit rate
// to ~86.5% -> model predicts 299us, measured 313us. Schedule (R1/R2/R3),
// L1 policy (R2), pipeline depth (R3) all proven null -- MSHR-saturated.
// L2-bypass instruments for the last ~15%: nt=neutral, asm sc1=fault,
// atomic-system=regression. This is the best-known operating point.
__global__ __launch_bounds__(BLK) void conv_main_h(
    const float* __restrict__ points,
    const v2f*   __restrict__ ph,
    const int*   __restrict__ indices,
    const float* __restrict__ w2,
    const float* __restrict__ bias,
    float*       __restrict__ out,
    int N) {
    __shared__ int sidx[BLK * (KT + 1)];  // pitch 17: 2-way bank alias = free

    const int tid = threadIdx.x;
    const int n0  = blockIdx.x * BLK;
    const int n   = n0 + tid;
    const bool valid = n < N;
    const int nc = valid ? n : (N - 1);

    const float px = __builtin_nontemporal_load(&points[nc * 3 + 0]);
    const float py = __builtin_nontemporal_load(&points[nc * 3 + 1]);
    const float pz = __builtin_nontemporal_load(&points[nc * 3 + 2]);

    float acc[OUTC];
#pragma unroll
    for (int l = 0; l < OUTC; ++l) {
        float a = bias[l] + w2[24 + l];           // k=0: dist feature = 1.0
        a = fmaf(px, w2[0 + l], a);
        a = fmaf(py, w2[8 + l], a);
        a = fmaf(pz, w2[16 + l], a);
        acc[l] = a;
    }

    for (int t = 0; t < 5; ++t) {
        __syncthreads();
        // Index staging: nt — stream-once, hinted out of L2 (R4 lesson:
        // never nt the gather; R9 lesson: never system-scope the stream).
#pragma unroll
        for (int i = 0; i < KT; ++i) {
            int e   = i * BLK + tid;
            int row = e >> 4;
            int col = e & 15;
            int gr  = n0 + row;
            if (gr >= N) gr = N - 1;
            sidx[row * (KT + 1) + col] =
                __builtin_nontemporal_load(&indices[gr * K_NB + 1 + t * KT + col]);
        }
        __syncthreads();

        // phase 1: pull all ids for this thread from LDS
        int ids[KT];
#pragma unroll
        for (int j = 0; j < KT; ++j)
            ids[j] = sidx[tid * (KT + 1) + j];

        // phase 2: issue ALL gathers back-to-back, PLAIN cached (L2-allocate)
        v2f r[KT];
#pragma unroll
        for (int j = 0; j < KT; ++j)
            r[j] = ph[ids[j]];

        // phase 3: consume (oldest first, vmcnt waits overlap issue)
#pragma unroll
        for (int j = 0; j < KT; ++j) {
            const int k = 1 + t * KT + j;
            F2H u0, u1; u0.f = r[j].x; u1.f = r[j].y;
            const float2 fxy = __half22float2(u0.h);
            const float  qx = fxy.x, qy = fxy.y;
            const float  qz = __half2float(__low2half(u1.h));
            const float dx = qx - px, dy = qy - py, dz = qz - pz;
            const float dist = fmaf(dx, dx, fmaf(dy, dy, fmaf(dz, dz, 1.0f)));
            const float* __restrict__ w = w2 + k * 32;  // uniform -> s_load
#pragma unroll
            for (int l = 0; l < OUTC; ++l) {
                acc[l] = fmaf(qx, w[l],
                         fmaf(qy, w[8 + l],
                         fmaf(qz, w[16 + l],
                         fmaf(dist, w[24 + l], acc[l]))));
            }
        }
    }

    if (valid) {
        v4f* o = (v4f*)(out + (long)n * OUTC);
        v4f lo, hi;
        lo.x = acc[0]; lo.y = acc[1]; lo.z = acc[2]; lo.w = acc[3];
        hi.x = acc[4]; hi.y = acc[5]; hi.z = acc[6]; hi.w = acc[7];
        __builtin_nontemporal_store(lo, o);
        __builtin_nontemporal_store(hi, o + 1);
    }
}

// ---------- fp32 fallback if ws too small ----------
__global__ __launch_bounds__(BLK) void conv_main_f32(
    const float* __restrict__ points,
    const int*   __restrict__ indices,
    const float* __restrict__ w2,
    const float* __restrict__ bias,
    float*       __restrict__ out,
    int N) {
    __shared__ int sidx[BLK * (KT + 1)];
    const int tid = threadIdx.x;
    const int n0  = blockIdx.x * BLK;
    const int n   = n0 + tid;
    const bool valid = n < N;
    const int nc = valid ? n : (N - 1);

    const float px = points[nc * 3 + 0];
    const float py = points[nc * 3 + 1];
    const float pz = points[nc * 3 + 2];
    float acc[OUTC];
#pragma unroll
    for (int l = 0; l < OUTC; ++l) {
        float a = bias[l] + w2[24 + l];
        a = fmaf(px, w2[0 + l], a);
        a = fmaf(py, w2[8 + l], a);
        a = fmaf(pz, w2[16 + l], a);
        acc[l] = a;
    }
    for (int t = 0; t < 5; ++t) {
        __syncthreads();
#pragma unroll
        for (int i = 0; i < KT; ++i) {
            int e = i * BLK + tid;
            int row = e >> 4, col = e & 15;
            int gr = n0 + row;
            if (gr >= N) gr = N - 1;
            sidx[row * (KT + 1) + col] = indices[gr * K_NB + 1 + t * KT + col];
        }
        __syncthreads();
#pragma unroll
        for (int j = 0; j < KT; ++j) {
            const int k  = 1 + t * KT + j;
            const int id = sidx[tid * (KT + 1) + j];
            const float qx = points[id * 3 + 0];
            const float qy = points[id * 3 + 1];
            const float qz = points[id * 3 + 2];
            const float dx = qx - px, dy = qy - py, dz = qz - pz;
            const float dist = fmaf(dx, dx, fmaf(dy, dy, fmaf(dz, dz, 1.0f)));
            const float* __restrict__ w = w2 + k * 32;
#pragma unroll
            for (int l = 0; l < OUTC; ++l) {
                acc[l] = fmaf(qx, w[l],
                         fmaf(qy, w[8 + l],
                         fmaf(qz, w[16 + l],
                         fmaf(dist, w[24 + l], acc[l]))));
            }
        }
    }
    if (valid) {
        float4* o = (float4*)(out + (long)n * OUTC);
        o[0] = make_float4(acc[0], acc[1], acc[2], acc[3]);
        o[1] = make_float4(acc[4], acc[5], acc[6], acc[7]);
    }
}

extern "C" void kernel_launch(void* const* d_in, const int* in_sizes, int n_in,
                              void* d_out, int out_size, void* d_ws, size_t ws_size,
                              hipStream_t stream) {
    const float* points  = (const float*)d_in[0];
    const int*   indices = (const int*)  d_in[1];
    const float* dw      = (const float*)d_in[2];
    const float* wt      = (const float*)d_in[3];
    const float* bias    = (const float*)d_in[4];
    float*       out     = (float*)d_out;

    const int N = in_sizes[0] / 3;

    const size_t ph_bytes = (size_t)N * 8;
    const size_t need     = ph_bytes + K_NB * 32 * sizeof(float);

    if (ws_size >= need) {
        v2f*   ph = (v2f*)d_ws;
        float* w2 = (float*)((char*)d_ws + ph_bytes);
        hipLaunchKernelGGL(prep_w2, dim3((K_NB * 32 + BLK - 1) / BLK), dim3(BLK),
                           0, stream, dw, wt, w2);
        hipLaunchKernelGGL(repack_points, dim3((N + BLK - 1) / BLK), dim3(BLK),
                           0, stream, points, ph, N);
        hipLaunchKernelGGL(conv_main_h, dim3((N + BLK - 1) / BLK), dim3(BLK),
                           0, stream, points, ph, indices, w2, bias, out, N);
    } else {
        float* w2 = (float*)d_ws;
        hipLaunchKernelGGL(prep_w2, dim3((K_NB * 32 + BLK - 1) / BLK), dim3(BLK),
                           0, stream, dw, wt, w2);
        hipLaunchKernelGGL(conv_main_f32, dim3((N + BLK - 1) / BLK), dim3(BLK),
                           0, stream, points, indices, w2, bias, out, N);
    }
}